// Round 1
// baseline (73.543 us; speedup 1.0000x reference)
//
#include <hip/hip_runtime.h>
#include <math.h>

// Problem constants (from reference): B=2048, F=512, K=32, P=3K+1=97
constexpr int Bn = 2048;
constexpr int Fn = 512;
constexpr int Kn = 32;
constexpr int Pn = 3 * Kn + 1;  // 97

// One block per batch row b (512 threads = 8 waves), one thread per feature f.
// All 97 parameter loads per thread are coalesced across lanes (stride-1 in f).
__global__ __launch_bounds__(Fn) void nsf_kernel(
    const float* __restrict__ x,
    const float* __restrict__ prm,
    const float* __restrict__ x0,
    const float* __restrict__ xf,
    float* __restrict__ y_out,
    float* __restrict__ ld_out)
{
    const int b = blockIdx.x;
    const int f = threadIdx.x;

    const float xv   = x[(size_t)b * Fn + f];
    const float x0v  = x0[f];
    const float span = xf[f] - x0v;

    const float* pb = prm + (size_t)b * Pn * Fn + f;

    // ---- softmax over width / height logits (kept in registers, static idx) ----
    float ew[Kn], eh[Kn];
    float mw = -INFINITY, mh = -INFINITY;
#pragma unroll
    for (int j = 0; j < Kn; ++j) { ew[j] = pb[(size_t)j * Fn];        mw = fmaxf(mw, ew[j]); }
#pragma unroll
    for (int j = 0; j < Kn; ++j) { eh[j] = pb[(size_t)(Kn + j) * Fn]; mh = fmaxf(mh, eh[j]); }
    float Sw = 0.f, Sh = 0.f;
#pragma unroll
    for (int j = 0; j < Kn; ++j) { float e = __expf(ew[j] - mw); ew[j] = e; Sw += e; }
#pragma unroll
    for (int j = 0; j < Kn; ++j) { float e = __expf(eh[j] - mh); eh[j] = e; Sh += e; }
    const float invSw = span / Sw;   // widths[j]  = ew[j] * invSw
    const float invSh = span / Sh;   // heights[j] = eh[j] * invSh

    // ---- fused cumsum + bin search + gather (predicated selects, no dyn idx) ----
    // bin = largest j in [0,31] with x > knots_x[j]; default 0 (reproduces clip)
    float cumx = 0.f, cumy = 0.f;
    float w_b = ew[0] * invSw, h_b = eh[0] * invSh;
    float xk = 0.f, yk = 0.f;
    int   bin = 0;
#pragma unroll
    for (int j = 0; j < Kn; ++j) {
        const float wj = ew[j] * invSw;
        const float hj = eh[j] * invSh;
        const bool  c  = xv > (x0v + cumx);   // x > knots_x[j]
        if (c) { w_b = wj; h_b = hj; xk = cumx; yk = cumy; bin = j; }
        cumx += wj; cumy += hj;
    }
    const float xk_b = x0v + xk;
    const float yk_b = x0v + yk;   // knots_y also offset by x0

    // ---- slopes: re-load the two needed logits (L1-hot), softplus = logaddexp(x,0)
    const float s0 = pb[(size_t)(2 * Kn + bin) * Fn];
    const float s1 = pb[(size_t)(2 * Kn + bin + 1) * Fn];
    const float d_k  = fmaxf(s0, 0.f) + log1pf(__expf(-fabsf(s0)));
    const float d_k1 = fmaxf(s1, 0.f) + log1pf(__expf(-fabsf(s1)));

    // ---- rational-quadratic spline ----
    const float s   = h_b / w_b;
    const float eps = (xv - xk_b) / w_b;
    const float ome = 1.f - eps;
    const float e1m = eps * ome;
    const float e2  = eps * eps;
    const float den = s + (d_k1 + d_k - 2.f * s) * e1m;
    const float yv  = yk_b + h_b * (s * e2 + d_k * e1m) / den;
    const float dy  = s * s * (d_k1 * e2 + 2.f * s * e1m + d_k * ome * ome) / (den * den);

    y_out[(size_t)b * Fn + f] = yv;

    // ---- block reduction of log(dy) over F=512 (8 waves) ----
    float ld = __logf(dy);
#pragma unroll
    for (int off = 32; off > 0; off >>= 1)
        ld += __shfl_down(ld, off, 64);

    __shared__ float wsum[Fn / 64];
    const int lane = f & 63;
    const int wv   = f >> 6;
    if (lane == 0) wsum[wv] = ld;
    __syncthreads();
    if (f == 0) {
        float t = 0.f;
#pragma unroll
        for (int i = 0; i < Fn / 64; ++i) t += wsum[i];
        ld_out[b] = t;
    }
}

extern "C" void kernel_launch(void* const* d_in, const int* in_sizes, int n_in,
                              void* d_out, int out_size, void* d_ws, size_t ws_size,
                              hipStream_t stream) {
    const float* x   = (const float*)d_in[0];
    const float* prm = (const float*)d_in[1];
    const float* x0  = (const float*)d_in[2];
    const float* xf  = (const float*)d_in[3];
    float* y  = (float*)d_out;                  // (B, F) flat
    float* ld = y + (size_t)Bn * Fn;            // (B,) appended

    nsf_kernel<<<Bn, Fn, 0, stream>>>(x, prm, x0, xf, y, ld);
}